// Round 1
// 746.286 us; speedup vs baseline: 1.1157x; 1.1157x over previous
//
#include <hip/hip_runtime.h>

// NgramAttentions, round 3: two-pass. Pass 1 gathers W_emb[seq] once -> bf16
// workspace in BOTH layouts (En [c][n][d], Et [c][d][n], 16.8 MB total).
// Pass 2 = proven S-orientation kernel, but E staging becomes coalesced bf16
// streams from workspace (no per-block gather, no fp32->bf16 convert, no
// column-scatter LDS writes). C=8, L=4096, N=4096, D=128.

typedef __bf16 bf16_t;
typedef bf16_t bf16x8 __attribute__((ext_vector_type(8)));
typedef float  f32x16 __attribute__((ext_vector_type(16)));
typedef float  f32x4  __attribute__((ext_vector_type(4)));

#define C_ 8
#define L_ 4096
#define N_ 4096
#define D_ 128

// ---------------- pass 1: gather + convert + dual-layout materialize ----------------
__global__ __launch_bounds__(256, 4) void prep_kernel(
    const int* __restrict__ seq,      // [C, N] int32
    const float* __restrict__ Wemb,   // [V, D]
    bf16_t* __restrict__ En,          // [C][N][D] bf16
    bf16_t* __restrict__ Et)          // [C][D][N] bf16
{
  __shared__ bf16_t T[128][132];      // [n_local][d], +4 pad

  const int bid = blockIdx.x;
  const int c   = bid & 7;            // same channel->XCD mapping as pass 2
  const int n0  = (bid >> 3) * 128;
  const int t   = threadIdx.x;

  // gather: thread t -> row n0+(t>>1), 64-float half (t&1)
  {
    const int row  = t >> 1;
    const int half = t & 1;
    const int idx  = seq[c * N_ + n0 + row];
    const float* src = Wemb + (size_t)idx * D_ + half * 64;
    bf16_t* dstE = En + ((size_t)c * N_ + n0 + row) * D_ + half * 64;
    #pragma unroll
    for (int j = 0; j < 8; ++j) {
      f32x4 a = *(const f32x4*)(src + j * 8);
      f32x4 b = *(const f32x4*)(src + j * 8 + 4);
      bf16x8 e = { (bf16_t)a[0], (bf16_t)a[1], (bf16_t)a[2], (bf16_t)a[3],
                   (bf16_t)b[0], (bf16_t)b[1], (bf16_t)b[2], (bf16_t)b[3] };
      *(bf16x8*)&T[row][half * 64 + j * 8] = e;
      *(bf16x8*)(dstE + j * 8) = e;
    }
  }
  __syncthreads();

  // transposed write: thread t -> d = t>>1, n-half = t&1
  {
    const int d  = t >> 1;
    const int nh = t & 1;
    bf16_t* dstT = Et + ((size_t)c * D_ + d) * N_ + n0 + nh * 64;
    #pragma unroll
    for (int j = 0; j < 8; ++j) {
      bf16x8 e;
      #pragma unroll
      for (int i = 0; i < 8; ++i) e[i] = T[nh * 64 + j * 8 + i][d];
      *(bf16x8*)(dstT + j * 8) = e;
    }
  }
}

// ---------------- pass 2: attention main loop ----------------
__global__ __launch_bounds__(512, 2) void ngram_attn_kernel(
    const float* __restrict__ hidden, // [L, D]
    const float* __restrict__ mask,   // [C, L, N]
    const bf16_t* __restrict__ EnWs,  // [C][N][D]
    const bf16_t* __restrict__ EtWs,  // [C][D][N]
    float* __restrict__ out)          // [L, C*D]
{
  // LDS (row stride 136 bf16 = 272 B -> b128 reads conflict-free as before)
  __shared__ bf16_t End[128][136];  // E tile [n][d]  (GEMM1 B)
  __shared__ bf16_t Et [128][136];  // E tile [d][n]  (GEMM2 B)
  __shared__ bf16_t Ps [128][136];  // P tile [l][n]  (GEMM2 A)
  __shared__ float  dpart[2][128];
  __shared__ float  dinv[128];

  const int bid  = blockIdx.x;
  const int c    = bid & 7;          // channel -> XCD-stable: E panel L2-resident
  const int l0   = (bid >> 3) * 128;
  const int tid  = threadIdx.x;
  const int lane = tid & 63;
  const int wv   = tid >> 6;
  const int mrow = lane & 31;
  const int hi   = lane >> 5;
  const int lsl  = wv & 3;           // l slab (32 rows)
  const int nh   = wv >> 2;          // GEMM1: n half | GEMM2: d half

  const float inv_temper = 0.08838834764831845f;  // 1/sqrt(128)
  const bf16_t* en_c = EnWs + (size_t)c * N_ * D_;
  const bf16_t* et_c = EtWs + (size_t)c * D_ * N_;

  // ---- H slab into registers once: A-frag layout [m=mrow][k contiguous]
  bf16x8 Ha[8];
  {
    const float* hrow = hidden + (size_t)(l0 + lsl * 32 + mrow) * D_ + hi * 8;
    #pragma unroll
    for (int ks = 0; ks < 8; ++ks) {
      f32x4 h0 = *(const f32x4*)(hrow + ks * 16);
      f32x4 h1 = *(const f32x4*)(hrow + ks * 16 + 4);
      Ha[ks] = (bf16x8){ (bf16_t)h0[0], (bf16_t)h0[1], (bf16_t)h0[2], (bf16_t)h0[3],
                         (bf16_t)h1[0], (bf16_t)h1[1], (bf16_t)h1[2], (bf16_t)h1[3] };
    }
  }

  const int lrow_base = lsl * 32 + 4 * hi;
  const int ncol      = nh * 64 + mrow;
  const float* mrow_base = mask + ((size_t)c * L_ + l0 + lrow_base) * N_ + ncol;

  bf16x8 enreg[4], etreg[4];  // prefetched E tile (both layouts), 64 B each/thread
  float  mreg[32];            // prefetched mask values

  // ---- preloop pipeline fill: E tile 0 + mask tile 0
  #pragma unroll
  for (int r = 0; r < 4; ++r) {
    int f = r * 512 + tid, rw = f >> 4, cb = (f & 15) * 8;
    enreg[r] = *(const bf16x8*)(en_c + (size_t)rw * D_ + cb);
    etreg[r] = *(const bf16x8*)(et_c + (size_t)rw * N_ + cb);
  }
  #pragma unroll
  for (int r = 0; r < 16; ++r) {
    const float* mp = mrow_base + (size_t)((r & 3) + 8 * (r >> 2)) * N_;
    mreg[2 * r + 0] = __builtin_nontemporal_load(mp);
    mreg[2 * r + 1] = __builtin_nontemporal_load(mp + 32);
  }

  f32x16 Oacc0, Oacc1;
  float dacc[16];
  #pragma unroll
  for (int i = 0; i < 16; ++i) { Oacc0[i] = 0.f; Oacc1[i] = 0.f; dacc[i] = 0.f; }

  #pragma unroll 1
  for (int nt = 0; nt < 32; ++nt) {
    __syncthreads();   // prev GEMM2 done reading End/Et/Ps

    // ---- stage E tile from prefetched regs (both layouts, b128 writes)
    #pragma unroll
    for (int r = 0; r < 4; ++r) {
      int f = r * 512 + tid, rw = f >> 4, cb = (f & 15) * 8;
      *(bf16x8*)&End[rw][cb] = enreg[r];
      *(bf16x8*)&Et [rw][cb] = etreg[r];
    }
    __syncthreads();

    // ---- GEMM1: S[l][n] = H . E^T
    f32x16 S0, S1;
    #pragma unroll
    for (int i = 0; i < 16; ++i) { S0[i] = 0.f; S1[i] = 0.f; }
    #pragma unroll
    for (int ks = 0; ks < 8; ++ks) {
      bf16x8 b0 = *(const bf16x8*)&End[nh * 64 + 0  + mrow][ks * 16 + hi * 8];
      bf16x8 b1 = *(const bf16x8*)&End[nh * 64 + 32 + mrow][ks * 16 + hi * 8];
      S0 = __builtin_amdgcn_mfma_f32_32x32x16_bf16(Ha[ks], b0, S0, 0, 0, 0);
      S1 = __builtin_amdgcn_mfma_f32_32x32x16_bf16(Ha[ks], b1, S1, 0, 0, 0);
    }

    // ---- issue next tile's E loads (regs free after stage; L2-resident stream)
    {
      int ntp = (nt < 31) ? nt + 1 : 31;
      const bf16_t* enb = en_c + (size_t)ntp * 128 * D_;
      const bf16_t* etb = et_c + ntp * 128;
      #pragma unroll
      for (int r = 0; r < 4; ++r) {
        int f = r * 512 + tid, rw = f >> 4, cb = (f & 15) * 8;
        enreg[r] = *(const bf16x8*)(enb + (size_t)rw * D_ + cb);
        etreg[r] = *(const bf16x8*)(etb + (size_t)rw * N_ + cb);
      }
    }

    // ---- exp * mask -> P (LDS) + running denominators
    #pragma unroll
    for (int r = 0; r < 16; ++r) {
      int lr = lsl * 32 + (r & 3) + 8 * (r >> 2) + 4 * hi;
      float m0 = fminf(fmaxf(mreg[2 * r + 0], 0.f), 1.f);
      float m1 = fminf(fmaxf(mreg[2 * r + 1], 0.f), 1.f);
      float w0 = __expf(S0[r] * inv_temper) * m0;
      float w1 = __expf(S1[r] * inv_temper) * m1;
      dacc[r] += w0 + w1;
      Ps[lr][nh * 64 + mrow]      = (bf16_t)w0;
      Ps[lr][nh * 64 + 32 + mrow] = (bf16_t)w1;
    }

    // ---- issue next tile's mask stream
    {
      int ntp = (nt < 31) ? nt + 1 : 31;
      const float* mb = mrow_base + (size_t)ntp * 128;
      #pragma unroll
      for (int r = 0; r < 16; ++r) {
        const float* mp = mb + (size_t)((r & 3) + 8 * (r >> 2)) * N_;
        mreg[2 * r + 0] = __builtin_nontemporal_load(mp);
        mreg[2 * r + 1] = __builtin_nontemporal_load(mp + 32);
      }
    }
    __syncthreads();   // Ps visible

    // ---- GEMM2: O[l][d] += P . E
    #pragma unroll
    for (int ks = 0; ks < 8; ++ks) {
      bf16x8 a  = *(const bf16x8*)&Ps[lsl * 32 + mrow][ks * 16 + hi * 8];
      bf16x8 b0 = *(const bf16x8*)&Et[nh * 64 + 0  + mrow][ks * 16 + hi * 8];
      bf16x8 b1 = *(const bf16x8*)&Et[nh * 64 + 32 + mrow][ks * 16 + hi * 8];
      Oacc0 = __builtin_amdgcn_mfma_f32_32x32x16_bf16(a, b0, Oacc0, 0, 0, 0);
      Oacc1 = __builtin_amdgcn_mfma_f32_32x32x16_bf16(a, b1, Oacc1, 0, 0, 0);
    }
  }

  // ---- finalize denominators
  #pragma unroll
  for (int r = 0; r < 16; ++r) {
    float v = dacc[r];
    v += __shfl_xor(v, 1, 64);
    v += __shfl_xor(v, 2, 64);
    v += __shfl_xor(v, 4, 64);
    v += __shfl_xor(v, 8, 64);
    v += __shfl_xor(v, 16, 64);
    if (mrow == 0)
      dpart[nh][lsl * 32 + (r & 3) + 8 * (r >> 2) + 4 * hi] = v;
  }
  __syncthreads();
  if (tid < 128)
    dinv[tid] = 1.0f / (dpart[0][tid] + dpart[1][tid] + 1e-10f);
  __syncthreads();

  // ---- epilogue: normalize + nontemporal store
  #pragma unroll
  for (int r = 0; r < 16; ++r) {
    int lr = lsl * 32 + (r & 3) + 8 * (r >> 2) + 4 * hi;
    float inv = dinv[lr];
    size_t base = (size_t)(l0 + lr) * (C_ * D_) + c * D_ + nh * 64 + mrow;
    __builtin_nontemporal_store(Oacc0[r] * inv, out + base);
    __builtin_nontemporal_store(Oacc1[r] * inv, out + base + 32);
  }
}

extern "C" void kernel_launch(void* const* d_in, const int* in_sizes, int n_in,
                              void* d_out, int out_size, void* d_ws, size_t ws_size,
                              hipStream_t stream) {
  (void)in_sizes; (void)n_in; (void)out_size; (void)ws_size;
  const int*   seq    = (const int*)d_in[0];
  const float* hidden = (const float*)d_in[1];
  const float* mask   = (const float*)d_in[2];
  // d_in[3] = channel_ids (unused), d_in[5] = W_channel (softmax over size-1 dim == 1)
  const float* Wemb   = (const float*)d_in[4];
  float* out = (float*)d_out;

  bf16_t* EnWs = (bf16_t*)d_ws;                        // [C][N][D]  8.4 MB
  bf16_t* EtWs = EnWs + (size_t)C_ * N_ * D_;          // [C][D][N]  8.4 MB

  prep_kernel<<<dim3(256), dim3(256), 0, stream>>>(seq, Wemb, EnWs, EtWs);
  ngram_attn_kernel<<<dim3(256), dim3(512), 0, stream>>>(hidden, mask, EnWs, EtWs, out);
}